// Round 1
// baseline (155.448 us; speedup 1.0000x reference)
//
#include <hip/hip_runtime.h>
#include <stdint.h>
#include <math.h>

#define HD 512
#define ID 1408
#define NEXP 8
#define NTOK 2048
#define NPAIRS 4096
#define NROWS 6144   // 4096 routed pairs + 2048 shared rows

typedef unsigned short u16;
typedef __attribute__((ext_vector_type(8))) __bf16 bf16x8;
typedef __attribute__((ext_vector_type(4))) float f32x4;

__device__ __forceinline__ u16 f2bf(float f) {
  union { float f; uint32_t u; } v; v.f = f;
  uint32_t u = v.u;
  u += 0x7FFFu + ((u >> 16) & 1u);   // RNE
  return (u16)(u >> 16);
}

__device__ __forceinline__ void gll16(const void* g, void* l) {
  __builtin_amdgcn_global_load_lds((const __attribute__((address_space(1))) void*)g,
                                   (__attribute__((address_space(3))) void*)l, 16, 0, 0);
}

// ---------------- cast x (f32) -> bf16 ----------------
__global__ void cast_x_kernel(const float* __restrict__ x, u16* __restrict__ xg) {
  int i = blockIdx.x * blockDim.x + threadIdx.x;   // NTOK*HD/4 threads
  float4 v = ((const float4*)x)[i];
  ushort4 o;
  o.x = f2bf(v.x); o.y = f2bf(v.y); o.z = f2bf(v.z); o.w = f2bf(v.w);
  ((ushort4*)xg)[i] = o;
}

// ---------- transpose + cast: dst[b][c][r] = bf16(src[b][r][c]) ----------
__global__ void transpose_cast_kernel(const float* __restrict__ src, u16* __restrict__ dst,
                                      int R, int C) {
  __shared__ float tile[32][33];
  int b = blockIdx.z;
  int c0 = blockIdx.x * 32, r0 = blockIdx.y * 32;
  const float* s = src + (size_t)b * R * C;
  u16* d = dst + (size_t)b * R * C;
  int tx = threadIdx.x, ty = threadIdx.y;  // (32,8)
#pragma unroll
  for (int j = 0; j < 4; ++j)
    tile[ty + 8 * j][tx] = s[(size_t)(r0 + ty + 8 * j) * C + (c0 + tx)];
  __syncthreads();
#pragma unroll
  for (int j = 0; j < 4; ++j)
    d[(size_t)(c0 + ty + 8 * j) * R + (r0 + tx)] = f2bf(tile[tx][ty + 8 * j]);
}

// ---------------- gate: fp32 logits, softmax, top-2 ----------------
__global__ __launch_bounds__(256) void gate_kernel(
    const float* __restrict__ x, const float* __restrict__ gw,
    float* __restrict__ scores, float* __restrict__ topw, int* __restrict__ topidx) {
  int t = blockIdx.x * 4 + (threadIdx.x >> 6);
  int lane = threadIdx.x & 63;
  float xv[8];
#pragma unroll
  for (int j = 0; j < 8; ++j) xv[j] = x[(size_t)t * HD + lane + 64 * j];
  float sc[8];
#pragma unroll
  for (int e = 0; e < 8; ++e) {
    float p = 0.f;
#pragma unroll
    for (int j = 0; j < 8; ++j) p += xv[j] * gw[e * HD + lane + 64 * j];
#pragma unroll
    for (int o = 32; o; o >>= 1) p += __shfl_xor(p, o);
    sc[e] = p;
  }
  float m = sc[0];
#pragma unroll
  for (int e = 1; e < 8; ++e) m = fmaxf(m, sc[e]);
  float ssum = 0.f;
#pragma unroll
  for (int e = 0; e < 8; ++e) { sc[e] = expf(sc[e] - m); ssum += sc[e]; }
  float is = 1.f / ssum;
#pragma unroll
  for (int e = 0; e < 8; ++e) sc[e] *= is;
  // top-2, ties -> lowest index (matches lax.top_k)
  int e0 = 0; float v0 = sc[0];
#pragma unroll
  for (int e = 1; e < 8; ++e) if (sc[e] > v0) { v0 = sc[e]; e0 = e; }
  int e1 = -1; float v1 = -1.f;
#pragma unroll
  for (int e = 0; e < 8; ++e) if (e != e0 && sc[e] > v1) { v1 = sc[e]; e1 = e; }
  if (lane == 0) {
#pragma unroll
    for (int e = 0; e < 8; ++e) scores[t * 8 + e] = sc[e];
    float d = v0 + v1 + 1e-20f;
    topw[t * 2] = v0 / d; topw[t * 2 + 1] = v1 / d;
    topidx[t * 2] = e0; topidx[t * 2 + 1] = e1;
  }
}

// ------- scatter: counts -> offsets -> permutation + inv map + aux loss -------
__global__ void scatter_kernel(const int* __restrict__ topidx, const float* __restrict__ scores,
                               int* __restrict__ pairTok, int* __restrict__ inv,
                               int* __restrict__ segOff, int* __restrict__ segN,
                               float* __restrict__ auxout) {
  __shared__ int cnt[8], offs[8], cur[8];
  __shared__ float partS[256];
  __shared__ int partC[256];
  int tid = threadIdx.x;
  if (tid < 8) { cnt[tid] = 0; cur[tid] = 0; }
  __syncthreads();
  for (int p = tid; p < NPAIRS; p += 256) atomicAdd(&cnt[topidx[p]], 1);
  __syncthreads();
  if (tid == 0) {
    int run = 0;
    for (int e = 0; e < 8; ++e) { offs[e] = run; segOff[e] = run; segN[e] = cnt[e]; run += cnt[e]; }
    segOff[8] = NPAIRS; segN[8] = NTOK;
  }
  __syncthreads();
  for (int p = tid; p < NPAIRS; p += 256) {
    int e = topidx[p];
    int pos = offs[e] + atomicAdd(&cur[e], 1);
    pairTok[pos] = p >> 1;
    inv[p] = pos;
  }
  // aux loss (deterministic reduction)
  int c = tid & 15;   // combo: b = c>>3, e = c&7
  int g = tid >> 4;   // group 0..15
  int b = c >> 3, e = c & 7;
  float ls = 0.f; int lc = 0;
  for (int jj = 0; jj < 64; ++jj) {
    int t = b * 1024 + (g + jj * 16);
    lc += (topidx[t * 2] == e) + (topidx[t * 2 + 1] == e);
    ls += scores[t * 8 + e];
  }
  partS[c * 16 + g] = ls; partC[c * 16 + g] = lc;
  __syncthreads();
  if (tid == 0) {
    float aux = 0.f;
    for (int bb = 0; bb < 2; ++bb) {
      float sb = 0.f;
      for (int ee = 0; ee < 8; ++ee) {
        float S = 0.f; int C = 0;
        for (int gg = 0; gg < 16; ++gg) { S += partS[(bb * 8 + ee) * 16 + gg]; C += partC[(bb * 8 + ee) * 16 + gg]; }
        sb += ((float)C / 256.0f) * (S / 1024.0f);
      }
      aux += sb;
    }
    *auxout = aux * 0.5f * 0.1f;
  }
}

// --------- GEMM1: act[p] = silu(x@Wg) * (x@Wu) per segment, bf16 MFMA ---------
__global__ __launch_bounds__(256, 2) void gemm1_kernel(
    const u16* __restrict__ Xg,
    const u16* __restrict__ Wgt, const u16* __restrict__ Wut,
    const u16* __restrict__ Wgst, const u16* __restrict__ Wust,
    const int* __restrict__ pairTok, const int* __restrict__ segOff,
    const int* __restrict__ segN, u16* __restrict__ act) {
  int s = blockIdx.z;
  int off = segOff[s], n = segN[s];
  int mt = blockIdx.y;
  if (mt * 128 >= n) return;
  int nt = blockIdx.x;
  const u16* Bg = (s < 8) ? Wgt + (size_t)s * ID * HD : Wgst;
  const u16* Bu = (s < 8) ? Wut + (size_t)s * ID * HD : Wust;

  __shared__ __align__(16) u16 Al[128 * 32];
  __shared__ __align__(16) u16 Bgl[128 * 32];
  __shared__ __align__(16) u16 Bul[128 * 32];

  int tid = threadIdx.x;
  int w = tid >> 6, lane = tid & 63;
  int r0 = tid >> 2, r1 = 64 + (tid >> 2);
  int kc = tid & 3;
  int pmax = off + n - 1;
  int pr0 = off + mt * 128 + r0; if (pr0 > pmax) pr0 = pmax;
  int pr1 = off + mt * 128 + r1; if (pr1 > pmax) pr1 = pmax;
  int tok0 = (s < 8) ? pairTok[pr0] : (pr0 - NPAIRS);
  int tok1 = (s < 8) ? pairTok[pr1] : (pr1 - NPAIRS);
  const u16* srcA0 = Xg + (size_t)tok0 * HD + kc * 8;
  const u16* srcA1 = Xg + (size_t)tok1 * HD + kc * 8;
  const u16* srcBg0 = Bg + (size_t)(nt * 128 + r0) * HD + kc * 8;
  const u16* srcBg1 = Bg + (size_t)(nt * 128 + r1) * HD + kc * 8;
  const u16* srcBu0 = Bu + (size_t)(nt * 128 + r0) * HD + kc * 8;
  const u16* srcBu1 = Bu + (size_t)(nt * 128 + r1) * HD + kc * 8;
  u16* ldsA0 = &Al[(w * 64) * 8];  u16* ldsA1 = &Al[(256 + w * 64) * 8];
  u16* ldsBg0 = &Bgl[(w * 64) * 8]; u16* ldsBg1 = &Bgl[(256 + w * 64) * 8];
  u16* ldsBu0 = &Bul[(w * 64) * 8]; u16* ldsBu1 = &Bul[(256 + w * 64) * 8];

  f32x4 accg[4][4], accu[4][4];
  f32x4 zz = {0.f, 0.f, 0.f, 0.f};
#pragma unroll
  for (int i = 0; i < 4; ++i)
#pragma unroll
    for (int j = 0; j < 4; ++j) { accg[i][j] = zz; accu[i][j] = zz; }

  int wm = w >> 1, wn = w & 1;
  int l15 = lane & 15, lh = lane >> 4;

  for (int kt = 0; kt < HD / 32; ++kt) {
    if (kt) __syncthreads();
    gll16(srcA0 + kt * 32, ldsA0);
    gll16(srcA1 + kt * 32, ldsA1);
    gll16(srcBg0 + kt * 32, ldsBg0);
    gll16(srcBg1 + kt * 32, ldsBg1);
    gll16(srcBu0 + kt * 32, ldsBu0);
    gll16(srcBu1 + kt * 32, ldsBu1);
    __syncthreads();
    bf16x8 a[4], bg[4], bu[4];
#pragma unroll
    for (int i = 0; i < 4; ++i) {
      a[i]  = *(const bf16x8*)&Al [(wm * 64 + i * 16 + l15) * 32 + lh * 8];
      bg[i] = *(const bf16x8*)&Bgl[(wn * 64 + i * 16 + l15) * 32 + lh * 8];
      bu[i] = *(const bf16x8*)&Bul[(wn * 64 + i * 16 + l15) * 32 + lh * 8];
    }
#pragma unroll
    for (int i = 0; i < 4; ++i)
#pragma unroll
      for (int j = 0; j < 4; ++j) {
        accg[i][j] = __builtin_amdgcn_mfma_f32_16x16x32_bf16(a[i], bg[j], accg[i][j], 0, 0, 0);
        accu[i][j] = __builtin_amdgcn_mfma_f32_16x16x32_bf16(a[i], bu[j], accu[i][j], 0, 0, 0);
      }
  }
  int base_row = mt * 128;
#pragma unroll
  for (int i = 0; i < 4; ++i)
#pragma unroll
    for (int j = 0; j < 4; ++j)
#pragma unroll
      for (int r = 0; r < 4; ++r) {
        int rl = wm * 64 + i * 16 + lh * 4 + r;
        if (base_row + rl < n) {
          int col = wn * 64 + j * 16 + l15;
          float gv = accg[i][j][r], uv = accu[i][j][r];
          float av = (gv / (1.f + expf(-gv))) * uv;
          act[(size_t)(off + base_row + rl) * ID + nt * 128 + col] = f2bf(av);
        }
      }
}

// --------- GEMM2: ybuf[p] = act[p] @ Wd^T, bf16 MFMA, f32 out ---------
__global__ __launch_bounds__(256, 2) void gemm2_kernel(
    const u16* __restrict__ act,
    const u16* __restrict__ Wdt, const u16* __restrict__ Wdst,
    const int* __restrict__ segOff, const int* __restrict__ segN,
    float* __restrict__ ybuf) {
  int s = blockIdx.z;
  int off = segOff[s], n = segN[s];
  int mt = blockIdx.y;
  if (mt * 128 >= n) return;
  int nt = blockIdx.x;
  const u16* B = (s < 8) ? Wdt + (size_t)s * HD * ID : Wdst;  // [512][1408]

  __shared__ __align__(16) u16 Al[128 * 32];
  __shared__ __align__(16) u16 Bl[128 * 32];
  int tid = threadIdx.x, w = tid >> 6, lane = tid & 63;
  int r0 = tid >> 2, r1 = 64 + (tid >> 2), kc = tid & 3;
  int pmax = off + n - 1;
  int p0 = off + mt * 128 + r0; if (p0 > pmax) p0 = pmax;
  int p1 = off + mt * 128 + r1; if (p1 > pmax) p1 = pmax;
  const u16* srcA0 = act + (size_t)p0 * ID + kc * 8;
  const u16* srcA1 = act + (size_t)p1 * ID + kc * 8;
  const u16* srcB0 = B + (size_t)(nt * 128 + r0) * ID + kc * 8;
  const u16* srcB1 = B + (size_t)(nt * 128 + r1) * ID + kc * 8;
  u16* ldsA0 = &Al[(w * 64) * 8]; u16* ldsA1 = &Al[(256 + w * 64) * 8];
  u16* ldsB0 = &Bl[(w * 64) * 8]; u16* ldsB1 = &Bl[(256 + w * 64) * 8];

  f32x4 acc[4][4];
  f32x4 zz = {0.f, 0.f, 0.f, 0.f};
#pragma unroll
  for (int i = 0; i < 4; ++i)
#pragma unroll
    for (int j = 0; j < 4; ++j) acc[i][j] = zz;
  int wm = w >> 1, wn = w & 1, l15 = lane & 15, lh = lane >> 4;

  for (int kt = 0; kt < ID / 32; ++kt) {
    if (kt) __syncthreads();
    gll16(srcA0 + kt * 32, ldsA0);
    gll16(srcA1 + kt * 32, ldsA1);
    gll16(srcB0 + kt * 32, ldsB0);
    gll16(srcB1 + kt * 32, ldsB1);
    __syncthreads();
    bf16x8 a[4], b[4];
#pragma unroll
    for (int i = 0; i < 4; ++i) {
      a[i] = *(const bf16x8*)&Al[(wm * 64 + i * 16 + l15) * 32 + lh * 8];
      b[i] = *(const bf16x8*)&Bl[(wn * 64 + i * 16 + l15) * 32 + lh * 8];
    }
#pragma unroll
    for (int i = 0; i < 4; ++i)
#pragma unroll
      for (int j = 0; j < 4; ++j)
        acc[i][j] = __builtin_amdgcn_mfma_f32_16x16x32_bf16(a[i], b[j], acc[i][j], 0, 0, 0);
  }
  int base_row = mt * 128;
#pragma unroll
  for (int i = 0; i < 4; ++i)
#pragma unroll
    for (int j = 0; j < 4; ++j)
#pragma unroll
      for (int r = 0; r < 4; ++r) {
        int rl = wm * 64 + i * 16 + lh * 4 + r;
        if (base_row + rl < n) {
          int col = wn * 64 + j * 16 + l15;
          ybuf[(size_t)(off + base_row + rl) * HD + nt * 128 + col] = acc[i][j][r];
        }
      }
}

// --------- combine: out[t] = w0*y(pair0) + w1*y(pair1) + y(shared) ---------
__global__ void combine_kernel(const float* __restrict__ ybuf, const float* __restrict__ topw,
                               const int* __restrict__ inv, float* __restrict__ out) {
  int t = blockIdx.x;
  int hd = threadIdx.x;  // 128 float4 lanes
  int i0 = inv[t * 2], i1 = inv[t * 2 + 1];
  float w0 = topw[t * 2], w1 = topw[t * 2 + 1];
  const float4* y4 = (const float4*)ybuf;
  float4 a = y4[(size_t)i0 * 128 + hd];
  float4 b = y4[(size_t)i1 * 128 + hd];
  float4 c = y4[(size_t)(NPAIRS + t) * 128 + hd];
  float4 o;
  o.x = w0 * a.x + w1 * b.x + c.x;
  o.y = w0 * a.y + w1 * b.y + c.y;
  o.z = w0 * a.z + w1 * b.z + c.z;
  o.w = w0 * a.w + w1 * b.w + c.w;
  ((float4*)out)[(size_t)t * 128 + hd] = o;
}

extern "C" void kernel_launch(void* const* d_in, const int* in_sizes, int n_in,
                              void* d_out, int out_size, void* d_ws, size_t ws_size,
                              hipStream_t stream) {
  const float* x   = (const float*)d_in[0];
  const float* gw  = (const float*)d_in[1];
  const float* Wg  = (const float*)d_in[2];
  const float* Wu  = (const float*)d_in[3];
  const float* Wd  = (const float*)d_in[4];
  const float* Wgs = (const float*)d_in[5];
  const float* Wus = (const float*)d_in[6];
  const float* Wds = (const float*)d_in[7];
  float* out = (float*)d_out;

  if (ws_size < (size_t)72 * 1024 * 1024) return;  // need ~71.1 MB scratch

  char* ws = (char*)d_ws;
  size_t o = 0;
  auto alloc = [&](size_t bytes) { char* p = ws + o; o += (bytes + 255) & ~(size_t)255; return p; };
  u16* Xg    = (u16*)alloc((size_t)NTOK * HD * 2);
  u16* Wgt   = (u16*)alloc((size_t)NEXP * ID * HD * 2);
  u16* Wut   = (u16*)alloc((size_t)NEXP * ID * HD * 2);
  u16* Wdt   = (u16*)alloc((size_t)NEXP * HD * ID * 2);
  u16* Wgst  = (u16*)alloc((size_t)ID * HD * 2);
  u16* Wust  = (u16*)alloc((size_t)ID * HD * 2);
  u16* Wdst  = (u16*)alloc((size_t)HD * ID * 2);
  u16* act   = (u16*)alloc((size_t)NROWS * ID * 2);
  float* ybuf   = (float*)alloc((size_t)NROWS * HD * 4);
  float* scores = (float*)alloc((size_t)NTOK * 8 * 4);
  float* topw   = (float*)alloc((size_t)NTOK * 2 * 4);
  int* topidx   = (int*)alloc((size_t)NTOK * 2 * 4);
  int* pairTok  = (int*)alloc((size_t)NPAIRS * 4);
  int* inv      = (int*)alloc((size_t)NPAIRS * 4);
  int* segOff   = (int*)alloc(64);
  int* segN     = (int*)alloc(64);

  dim3 tb(32, 8);
  cast_x_kernel<<<NTOK * HD / 4 / 256, 256, 0, stream>>>(x, Xg);
  transpose_cast_kernel<<<dim3(ID / 32, HD / 32, NEXP), tb, 0, stream>>>(Wg, Wgt, HD, ID);
  transpose_cast_kernel<<<dim3(ID / 32, HD / 32, NEXP), tb, 0, stream>>>(Wu, Wut, HD, ID);
  transpose_cast_kernel<<<dim3(HD / 32, ID / 32, NEXP), tb, 0, stream>>>(Wd, Wdt, ID, HD);
  transpose_cast_kernel<<<dim3(ID / 32, HD / 32, 1), tb, 0, stream>>>(Wgs, Wgst, HD, ID);
  transpose_cast_kernel<<<dim3(ID / 32, HD / 32, 1), tb, 0, stream>>>(Wus, Wust, HD, ID);
  transpose_cast_kernel<<<dim3(HD / 32, ID / 32, 1), tb, 0, stream>>>(Wds, Wdst, ID, HD);
  gate_kernel<<<NTOK / 4, 256, 0, stream>>>(x, gw, scores, topw, topidx);
  scatter_kernel<<<1, 256, 0, stream>>>(topidx, scores, pairTok, inv, segOff, segN,
                                        out + (size_t)NTOK * HD);
  gemm1_kernel<<<dim3(ID / 128, 16, 9), 256, 0, stream>>>(Xg, Wgt, Wut, Wgst, Wust,
                                                          pairTok, segOff, segN, act);
  gemm2_kernel<<<dim3(HD / 128, 16, 9), 256, 0, stream>>>(act, Wdt, Wdst, segOff, segN, ybuf);
  combine_kernel<<<NTOK, 128, 0, stream>>>(ybuf, topw, inv, out);
}